// Round 6
// baseline (122.515 us; speedup 1.0000x reference)
//
#include <hip/hip_runtime.h>

#define LPOS 256
#define CCH 20
#define BB 4096
#define LC 5120   // LPOS*CCH

// ---------------- Kernel 1: seq extraction + linear term -------------------
__global__ __launch_bounds__(256) void k_prepare(
    const float* __restrict__ x_lc, const float* __restrict__ theta_0,
    const float* __restrict__ theta_lc, unsigned char* __restrict__ seqB,
    float* __restrict__ out)
{
    const int b = blockIdx.x;
    const int l = threadIdx.x;
    const float* xp = x_lc + (size_t)b * LC + (size_t)l * CCH;
    const float4* xp4 = reinterpret_cast<const float4*>(xp);
    float v[CCH];
#pragma unroll
    for (int q = 0; q < 5; ++q) {
        float4 t = xp4[q];
        v[q * 4 + 0] = t.x; v[q * 4 + 1] = t.y;
        v[q * 4 + 2] = t.z; v[q * 4 + 3] = t.w;
    }
    int s = 0; float best = v[0];
#pragma unroll
    for (int c = 1; c < CCH; ++c) { if (v[c] > best) { best = v[c]; s = c; } }

    seqB[(size_t)b * LPOS + l] = (unsigned char)s;

    float lin = theta_lc[l * CCH + s];
#pragma unroll
    for (int off = 32; off > 0; off >>= 1) lin += __shfl_down(lin, off, 64);
    __shared__ float partial[4];
    const int wave = threadIdx.x >> 6;
    const int lane = threadIdx.x & 63;
    if (lane == 0) partial[wave] = lin;
    __syncthreads();
    if (threadIdx.x == 0)
        out[b] = theta_0[0] + partial[0] + partial[1] + partial[2] + partial[3];
}

// ---------------- Kernel 2: masked pairwise quadratic form -----------------
// quad[b] = sum_{l1<l2} Theta[l1,s1,l2,s2] (one-hot x => pure table lookups).
// Block (tile, g): batches [tile*512,+512), rows l1 in {g, 254-g}.
// l2 in absolute 8-aligned chunks m (32 per row); chunk table = LDS [j][s1][s2]
// (3200 f32, j-major, padded to 13 KB-segments), double-buffered, staged with
// global_load_lds. Small chunks + 512-thread blocks give 4 blocks/CU
// (32 waves): other blocks' gather bursts hide each block's vmcnt(0) drain.
#define QTHREADS 512
#define TILEB 512
#define NTILES (BB / TILEB)   // 8
#define NGROUPS 128
#define CHUNK 8
#define NM (LPOS / CHUNK)     // 32 chunks per row
#define TBL (CHUNK * CCH * CCH)   // 3200 f32 payload
#define SEGS 13                   // 13 x 1KB wave segments (last half-padded)
#define TBLP (SEGS * 256)         // 3328 f32 buffer stride (13312 B)

__global__ __launch_bounds__(QTHREADS) void k_quad(
    const float* __restrict__ Theta,          // (5120, 5120) f32 row-major
    const unsigned char* __restrict__ seqB,   // (B, L)
    float* __restrict__ out)
{
    __shared__ float Tl[2 * TBLP];   // 26624 B -> 4 blocks/CU within 160 KB

    const int tile = blockIdx.x;
    const int g    = blockIdx.y;
    const int tid  = threadIdx.x;
    const int b    = tile * TILEB + tid;
    const int wave = tid >> 6;
    const int lane = tid & 63;

    const unsigned char* sb = seqB + (size_t)b * LPOS;
    const uint2* sb2 = reinterpret_cast<const uint2*>(sb);

    const int l1a = g, l1b = 254 - g;
    const int m0a = (l1a + 1) >> 3, jloa = (l1a + 1) & 7;
    const int m0b = (l1b + 1) >> 3, jlob = (l1b + 1) & 7;
    const int n1 = NM - m0a;
    const int NT = (g == 127) ? n1 : n1 + (NM - m0b);

    const int basea = (int)sb[l1a] * CCH;   // s1*20
    const int baseb = (int)sb[l1b] * CCH;

    // chunk t -> (l1, m, gather base, jlo); all wave-uniform except base
    auto chunk_params = [&](int t, int& l1, int& m, int& base, int& jlo) {
        if (t < n1) { l1 = l1a; m = m0a + t; base = basea; jlo = (t == 0) ? jloa : 0; }
        else { l1 = l1b; m = m0b + (t - n1); base = baseb; jlo = (t == n1) ? jlob : 0; }
    };

    // Stage chunk (l1, m) into buffer dst: 13 segments x 64 lanes x 16 B.
    // f32-quad u = seg*64+lane covers table elems 4u..4u+3: r = u/5 (= j*20+s1),
    // c = u%5 -> global row (l1*20+s1), cols (m*8+j)*20 + 4c..+3. Quads with
    // u >= 800 are pad: clamp their source to quad 0 (garbage lands in LDS pad).
    auto stage = [&](int l1, int m, int dst) {
#pragma unroll
        for (int k = 0; k < 2; ++k) {
            const int seg = wave + k * 8;
            if (seg < SEGS) {
                const int u = seg * 64 + lane;
                const int uc = (u < TBL / 4) ? u : 0;
                const int r = uc / 5, c = uc - r * 5;
                const int j = r / CCH, s1 = r - j * CCH;
                const float* gp = Theta + (size_t)(l1 * CCH + s1) * LC
                                        + (m * CHUNK + j) * CCH + c * 4;
                float* lp = Tl + dst * TBLP + seg * 256;   // wave-uniform dest
                __builtin_amdgcn_global_load_lds(
                    (const __attribute__((address_space(1))) void*)gp,
                    (__attribute__((address_space(3))) void*)lp, 16, 0, 0);
            }
        }
    };

    // prologue: stage chunk 0 -> buf 0; prefetch its seq word
    uint2 sq;
    {
        int l1, m, base, jlo; chunk_params(0, l1, m, base, jlo);
        stage(l1, m, 0);
        sq = sb2[m];
    }
    __syncthreads();   // implicit vmcnt(0) drain -> buf 0 ready

    float acc = 0.f;
    for (int t = 0; t < NT; ++t) {
        const int cur = t & 1;
        int l1, m, base, jlo; chunk_params(t, l1, m, base, jlo);
        const unsigned w0 = sq.x, w1 = sq.y;       // current chunk's 8 indices
        if (t + 1 < NT) {                  // issue next chunk's async loads
            int l1n, mn, bn, jn; chunk_params(t + 1, l1n, mn, bn, jn);
            stage(l1n, mn, cur ^ 1);
            sq = sb2[mn];                  // prefetch next seq word
        }
        const float* T = Tl + cur * TBLP + base;
        if (jlo) {                          // ragged first chunk of a row
#pragma unroll
            for (int j = 0; j < CHUNK; ++j) {
                const unsigned w = (j < 4) ? w0 : w1;
                const int s2 = (w >> ((j & 3) * 8)) & 0xFF;
                float v = T[j * 400 + s2];
                acc += (j >= jlo) ? v : 0.f;
            }
        } else {
#pragma unroll
            for (int j = 0; j < CHUNK; ++j) {
                const unsigned w = (j < 4) ? w0 : w1;
                const int s2 = (w >> ((j & 3) * 8)) & 0xFF;
                acc += T[j * 400 + s2];
            }
        }
        __syncthreads();   // gathers done + next buffer's DMA drained
    }
    atomicAdd(&out[b], acc);
}

extern "C" void kernel_launch(void* const* d_in, const int* in_sizes, int n_in,
                              void* d_out, int out_size, void* d_ws, size_t ws_size,
                              hipStream_t stream) {
    const float* x_lc       = (const float*)d_in[0];
    const float* theta_0    = (const float*)d_in[1];
    const float* theta_lc   = (const float*)d_in[2];
    const float* theta_lclc = (const float*)d_in[3];
    // d_in[4] = mask (bool) — implicit: we only iterate l2 > l1.
    float* out = (float*)d_out;
    unsigned char* seqB = (unsigned char*)d_ws;   // B*L = 1 MB

    k_prepare<<<dim3(BB), dim3(256), 0, stream>>>(x_lc, theta_0, theta_lc, seqB, out);
    k_quad<<<dim3(NTILES, NGROUPS), dim3(QTHREADS), 0, stream>>>(theta_lclc, seqB, out);
}

// Round 7
// 101.788 us; speedup vs baseline: 1.2036x; 1.2036x over previous
//
#include <hip/hip_runtime.h>

#define LPOS 256
#define CCH 20
#define BB 4096
#define LC 5120   // LPOS*CCH

// ---------------- Kernel 1: seq extraction + linear term -------------------
__global__ __launch_bounds__(256) void k_prepare(
    const float* __restrict__ x_lc, const float* __restrict__ theta_0,
    const float* __restrict__ theta_lc, unsigned char* __restrict__ seqB,
    float* __restrict__ out)
{
    const int b = blockIdx.x;
    const int l = threadIdx.x;
    const float* xp = x_lc + (size_t)b * LC + (size_t)l * CCH;
    const float4* xp4 = reinterpret_cast<const float4*>(xp);
    float v[CCH];
#pragma unroll
    for (int q = 0; q < 5; ++q) {
        float4 t = xp4[q];
        v[q * 4 + 0] = t.x; v[q * 4 + 1] = t.y;
        v[q * 4 + 2] = t.z; v[q * 4 + 3] = t.w;
    }
    int s = 0; float best = v[0];
#pragma unroll
    for (int c = 1; c < CCH; ++c) { if (v[c] > best) { best = v[c]; s = c; } }

    seqB[(size_t)b * LPOS + l] = (unsigned char)s;

    float lin = theta_lc[l * CCH + s];
#pragma unroll
    for (int off = 32; off > 0; off >>= 1) lin += __shfl_down(lin, off, 64);
    __shared__ float partial[4];
    const int wave = threadIdx.x >> 6;
    const int lane = threadIdx.x & 63;
    if (lane == 0) partial[wave] = lin;
    __syncthreads();
    if (threadIdx.x == 0)
        out[b] = theta_0[0] + partial[0] + partial[1] + partial[2] + partial[3];
}

// ---------------- Kernel 2: masked pairwise quadratic form -----------------
// quad[b] = sum_{l1<l2} Theta[l1,s1,l2,s2] (one-hot x => pure table lookups).
// Block (tile, g): batches [tile*1024,+1024), rows l1 in {g, 254-g}.
// l2 in absolute 8-aligned chunks m; chunk table = LDS [j][s1][s2] (3200 f32
// padded to 16 x 1KB segments), THREE-deep rotating buffers staged with
// global_load_lds, ONE load per wave per chunk (uniform vmcnt accounting).
// Sync per chunk: s_waitcnt vmcnt(1) lgkmcnt(0) + raw s_barrier — the
// pipeline never drains vmcnt to 0 in the main loop (T3+T4).
#define QTHREADS 1024
#define TILEB 1024
#define NTILES (BB / TILEB)   // 4
#define NGROUPS 128
#define CHUNK 8
#define NM (LPOS / CHUNK)     // 32 chunks per row
#define NQUADS 800            // 3200 f32 payload / 4
#define SEGS 16               // 16 x 1KB wave segments (12.5 real + pad)
#define TBLP (SEGS * 256)     // 4096 f32 buffer stride (16 KB)
#define NBUF 3

__global__ __launch_bounds__(QTHREADS) void k_quad(
    const float* __restrict__ Theta,          // (5120, 5120) f32 row-major
    const unsigned char* __restrict__ seqB,   // (B, L)
    float* __restrict__ out)
{
    __shared__ float Tl[NBUF * TBLP];   // 48 KB -> 2 blocks/CU (wave-limited)

    const int tile = blockIdx.x;
    const int g    = blockIdx.y;
    const int tid  = threadIdx.x;
    const int b    = tile * TILEB + tid;
    const int wave = tid >> 6;
    const int lane = tid & 63;

    const unsigned char* sb = seqB + (size_t)b * LPOS;
    const uint2* sb2 = reinterpret_cast<const uint2*>(sb);

    const int l1a = g, l1b = 254 - g;
    const int m0a = (l1a + 1) >> 3, jloa = (l1a + 1) & 7;
    const int m0b = (l1b + 1) >> 3, jlob = (l1b + 1) & 7;
    const int n1 = NM - m0a;
    const int NT = (g == 127) ? n1 : n1 + (NM - m0b);

    const int basea = (int)sb[l1a] * CCH;   // s1*20
    const int baseb = (int)sb[l1b] * CCH;

    // chunk t -> (l1, m, gather base, jlo); all wave-uniform except base
    auto chunk_params = [&](int t, int& l1, int& m, int& base, int& jlo) {
        if (t < n1) { l1 = l1a; m = m0a + t; base = basea; jlo = (t == 0) ? jloa : 0; }
        else { l1 = l1b; m = m0b + (t - n1); base = baseb; jlo = (t == n1) ? jlob : 0; }
    };

    // Stage chunk (l1, m) into buffer dst. Each wave issues EXACTLY ONE
    // 16B/lane global_load_lds (seg = wave). f32-quad u = wave*64+lane maps
    // to table elems 4u..4u+3: r = u/5 (= j*20+s1), c = u%5 -> global row
    // (l1*20+s1), cols (m*8+j)*20 + 4c..+3. Quads u > 799 are pad: source
    // clamped to quad 799, lands in LDS pad (offsets 12800..16383 B).
    auto stage = [&](int l1, int m, int dst) {
        const int u = wave * 64 + lane;
        const int uc = (u < NQUADS) ? u : (NQUADS - 1);
        const int r = uc / 5, c = uc - r * 5;
        const int j = r / CCH, s1 = r - j * CCH;
        const float* gp = Theta + (size_t)(l1 * CCH + s1) * LC
                                + (m * CHUNK + j) * CCH + c * 4;
        float* lp = Tl + dst * TBLP + wave * 256;   // wave-uniform dest
        __builtin_amdgcn_global_load_lds(
            (const __attribute__((address_space(1))) void*)gp,
            (__attribute__((address_space(3))) void*)lp, 16, 0, 0);
    };

    // prologue: stage chunks 0,1 -> bufs 0,1; fetch chunk 0's seq word
    uint2 sq;
    {
        int l1, m, base, jlo;
        chunk_params(0, l1, m, base, jlo);
        stage(l1, m, 0);
        sq = sb2[m];
        chunk_params(1, l1, m, base, jlo);   // NT >= 16 always
        stage(l1, m, 1);
    }

    float acc = 0.f;
    for (int t = 0; t < NT; ++t) {
        int l1, m, base, jlo; chunk_params(t, l1, m, base, jlo);
        const unsigned w0 = sq.x, w1 = sq.y;   // current chunk's 8 indices

        // ---- chunk boundary: counted wait, never vmcnt(0) ----
        __builtin_amdgcn_sched_barrier(0);
        asm volatile("s_waitcnt vmcnt(1) lgkmcnt(0)" ::: "memory");
        __builtin_amdgcn_s_barrier();
        __builtin_amdgcn_sched_barrier(0);

        // issue stage(t+2) into buf (t+2)%3 (whose last reader was t-1,
        // barrier-protected). Tail: clamped duplicate keeps vmcnt uniform;
        // duplicate writes identical bytes (benign).
        {
            int tc = t + 2; if (tc >= NT) tc = NT - 1;
            int l1n, mn, bn, jn; chunk_params(tc, l1n, mn, bn, jn);
            stage(l1n, mn, (t + 2) % NBUF);
            int ts = t + 1; if (ts >= NT) ts = NT - 1;
            int l1s, ms, bs_, js; chunk_params(ts, l1s, ms, bs_, js);
            sq = sb2[ms];                     // prefetch next seq word
        }

        // gather chunk t from buf t%3 (branchless ragged mask: jlo==0 -> all)
        const float* T = Tl + (t % NBUF) * TBLP + base;
#pragma unroll
        for (int j = 0; j < CHUNK; ++j) {
            const unsigned w = (j < 4) ? w0 : w1;
            const int s2 = (w >> ((j & 3) * 8)) & 0xFF;
            float v = T[j * 400 + s2];
            acc += (j >= jlo) ? v : 0.f;
        }
    }
    atomicAdd(&out[b], acc);
}

extern "C" void kernel_launch(void* const* d_in, const int* in_sizes, int n_in,
                              void* d_out, int out_size, void* d_ws, size_t ws_size,
                              hipStream_t stream) {
    const float* x_lc       = (const float*)d_in[0];
    const float* theta_0    = (const float*)d_in[1];
    const float* theta_lc   = (const float*)d_in[2];
    const float* theta_lclc = (const float*)d_in[3];
    // d_in[4] = mask (bool) — implicit: we only iterate l2 > l1.
    float* out = (float*)d_out;
    unsigned char* seqB = (unsigned char*)d_ws;   // B*L = 1 MB

    k_prepare<<<dim3(BB), dim3(256), 0, stream>>>(x_lc, theta_0, theta_lc, seqB, out);
    k_quad<<<dim3(NTILES, NGROUPS), dim3(QTHREADS), 0, stream>>>(theta_lclc, seqB, out);
}

// Round 8
// 95.690 us; speedup vs baseline: 1.2803x; 1.0637x over previous
//
#include <hip/hip_runtime.h>

#define LPOS 256
#define CCH 20
#define BB 4096
#define LC 5120   // LPOS*CCH

// seqC layout: uint4[16][4096] — entry (mw, b) holds the 16 bytes
// s(b, l = 16*mw .. 16*mw+15). Coalesced: consecutive b = consecutive 16B.

// ---------------- Kernel 1: seq extraction + linear term -------------------
__global__ __launch_bounds__(256) void k_prepare(
    const float* __restrict__ x_lc, const float* __restrict__ theta_0,
    const float* __restrict__ theta_lc, unsigned char* __restrict__ seqC,
    float* __restrict__ out)
{
    const int b = blockIdx.x;
    const int l = threadIdx.x;
    const float* xp = x_lc + (size_t)b * LC + (size_t)l * CCH;
    const float4* xp4 = reinterpret_cast<const float4*>(xp);
    float v[CCH];
#pragma unroll
    for (int q = 0; q < 5; ++q) {
        float4 t = xp4[q];
        v[q * 4 + 0] = t.x; v[q * 4 + 1] = t.y;
        v[q * 4 + 2] = t.z; v[q * 4 + 3] = t.w;
    }
    int s = 0; float best = v[0];
#pragma unroll
    for (int c = 1; c < CCH; ++c) { if (v[c] > best) { best = v[c]; s = c; } }

    // seqC[(l>>4)][b] byte (l&15)
    seqC[(size_t)(l >> 4) * (BB * 16) + (size_t)b * 16 + (l & 15)] =
        (unsigned char)s;

    float lin = theta_lc[l * CCH + s];
#pragma unroll
    for (int off = 32; off > 0; off >>= 1) lin += __shfl_down(lin, off, 64);
    __shared__ float partial[4];
    const int wave = threadIdx.x >> 6;
    const int lane = threadIdx.x & 63;
    if (lane == 0) partial[wave] = lin;
    __syncthreads();
    if (threadIdx.x == 0)
        out[b] = theta_0[0] + partial[0] + partial[1] + partial[2] + partial[3];
}

// ---------------- Kernel 2: masked pairwise quadratic form -----------------
// quad[b] = sum_{l1<l2} Theta[l1,s1,l2,s2]. INVERTED decomposition: block
// (c, g) owns rows l1 in {g, 254-g} and l2-chunks m ∈ {m0+c, m0+c+8} (16-wide
// chunks); it stages each chunk table ONCE and sweeps ALL 4096 batches
// (thread t accumulates batches b = i*512+t, i=0..7, in registers).
// Staging/barrier cost amortized over 1024 gathers/thread-chunk: ~90% of
// dynamic instructions are the irreducible LDS gathers.
#define QT 512
#define NC 8                 // chunk-slice blocks per g
#define TBL 6400             // 16*20*20 f32 = 25.6 KB (exactly 25 KB-segments)

__global__ __launch_bounds__(QT, 8) void k_quad(
    const float* __restrict__ Theta,          // (5120, 5120) f32 row-major
    const uint4* __restrict__ seqC,           // [16][4096]
    float* __restrict__ out)
{
    __shared__ float Tl[TBL];    // 25.6 KB -> 4 blocks/CU (32 waves, 100%)

    const int c   = blockIdx.x;  // 0..7
    const int g   = blockIdx.y;  // 0..127
    const int tid = threadIdx.x;
    const int wave = tid >> 6;
    const int lane = tid & 63;

    float acc[8];
#pragma unroll
    for (int i = 0; i < 8; ++i) acc[i] = 0.f;

    const int l1arr[2] = { g, 254 - g };
    const int nl1 = (g == 127) ? 1 : 2;

    for (int q = 0; q < nl1; ++q) {
        const int l1 = l1arr[q];
        const int m0  = (l1 + 1) >> 4;
        const int jlo = (l1 + 1) & 15;

        // base[i] = s1(b_i, l1) * 20, from byte (l1&15) of seqC[l1>>4][b_i]
        int base[8];
        {
            const int mw = l1 >> 4;
            const int wsel = (l1 >> 2) & 3;
            const int sh = (l1 & 3) * 8;
#pragma unroll
            for (int i = 0; i < 8; ++i) {
                const uint4 u = seqC[(size_t)mw * BB + i * QT + tid];
                const unsigned w = (wsel == 0) ? u.x : (wsel == 1) ? u.y
                                 : (wsel == 2) ? u.z : u.w;
                base[i] = (int)((w >> sh) & 0xFFu) * CCH;
            }
        }

        for (int m = m0 + c; m < 16; m += NC) {
            __syncthreads();   // prior chunk's gathers complete
            // Stage chunk (l1, m): 25 segs x 64 lanes x 16 B via gload_lds.
            // f32-quad u = seg*64+lane -> elems 4u..4u+3: r = u/5 (= j*20+s1),
            // cc = u%5 -> global row (l1*20+s1), cols (m*16+j)*20 + 4cc..+3.
#pragma unroll
            for (int k = 0; k < 4; ++k) {
                const int seg = wave + 8 * k;      // wave-uniform
                if (seg < 25) {
                    const int u = seg * 64 + lane;           // < 1600
                    const int r = u / 5, cc = u - r * 5;
                    const int j = r / CCH, s1 = r - j * CCH;
                    const float* gp = Theta + (size_t)(l1 * CCH + s1) * LC
                                            + (m * 16 + j) * CCH + cc * 4;
                    float* lp = Tl + seg * 256;              // wave-uniform
                    __builtin_amdgcn_global_load_lds(
                        (const __attribute__((address_space(1))) void*)gp,
                        (__attribute__((address_space(3))) void*)lp, 16, 0, 0);
                }
            }
            __syncthreads();   // table ready (drains DMA)

            const int jl = (m == m0) ? jlo : 0;
            if (jl == 0) {
#pragma unroll
                for (int i = 0; i < 8; ++i) {
                    const uint4 u = seqC[(size_t)m * BB + i * QT + tid];
#pragma unroll
                    for (int j = 0; j < 16; ++j) {
                        const unsigned w = (j < 4) ? u.x : (j < 8) ? u.y
                                         : (j < 12) ? u.z : u.w;
                        const int s2 = (w >> ((j & 3) * 8)) & 0xFF;
                        acc[i] += Tl[j * 400 + base[i] + s2];
                    }
                }
            } else {           // ragged first chunk of this row (uniform)
#pragma unroll
                for (int i = 0; i < 8; ++i) {
                    const uint4 u = seqC[(size_t)m * BB + i * QT + tid];
#pragma unroll
                    for (int j = 0; j < 16; ++j) {
                        const unsigned w = (j < 4) ? u.x : (j < 8) ? u.y
                                         : (j < 12) ? u.z : u.w;
                        const int s2 = (w >> ((j & 3) * 8)) & 0xFF;
                        const float v = Tl[j * 400 + base[i] + s2];
                        acc[i] += (j >= jl) ? v : 0.f;
                    }
                }
            }
        }
    }

#pragma unroll
    for (int i = 0; i < 8; ++i)
        atomicAdd(&out[i * QT + tid], acc[i]);
}

extern "C" void kernel_launch(void* const* d_in, const int* in_sizes, int n_in,
                              void* d_out, int out_size, void* d_ws, size_t ws_size,
                              hipStream_t stream) {
    const float* x_lc       = (const float*)d_in[0];
    const float* theta_0    = (const float*)d_in[1];
    const float* theta_lc   = (const float*)d_in[2];
    const float* theta_lclc = (const float*)d_in[3];
    // d_in[4] = mask (bool) — implicit: we only iterate l2 > l1.
    float* out = (float*)d_out;
    unsigned char* seqC = (unsigned char*)d_ws;   // 16*4096*16 B = 1 MB

    k_prepare<<<dim3(BB), dim3(256), 0, stream>>>(x_lc, theta_0, theta_lc, seqC, out);
    k_quad<<<dim3(NC, 128), dim3(QT), 0, stream>>>(
        theta_lclc, (const uint4*)seqC, out);
}

// Round 9
// 68.804 us; speedup vs baseline: 1.7806x; 1.3908x over previous
//
#include <hip/hip_runtime.h>

#define LPOS 256
#define CCH 20
#define BB 4096
#define LC 5120   // LPOS*CCH

// seqC layout: uint2[32][4096] — entry (mw, b) holds bytes s(b, l=8mw..8mw+7).
// Consecutive b = consecutive 8B => fully coalesced chunk-index fetches.

// ---------------- Kernel 1: seq extraction + linear term -------------------
__global__ __launch_bounds__(256) void k_prepare(
    const float* __restrict__ x_lc, const float* __restrict__ theta_0,
    const float* __restrict__ theta_lc, unsigned char* __restrict__ seqC,
    float* __restrict__ out)
{
    const int b = blockIdx.x;
    const int l = threadIdx.x;
    const float* xp = x_lc + (size_t)b * LC + (size_t)l * CCH;
    const float4* xp4 = reinterpret_cast<const float4*>(xp);
    float v[CCH];
#pragma unroll
    for (int q = 0; q < 5; ++q) {
        float4 t = xp4[q];
        v[q * 4 + 0] = t.x; v[q * 4 + 1] = t.y;
        v[q * 4 + 2] = t.z; v[q * 4 + 3] = t.w;
    }
    int s = 0; float best = v[0];
#pragma unroll
    for (int c = 1; c < CCH; ++c) { if (v[c] > best) { best = v[c]; s = c; } }

    seqC[((size_t)(l >> 3) * BB + b) * 8 + (l & 7)] = (unsigned char)s;

    float lin = theta_lc[l * CCH + s];
#pragma unroll
    for (int off = 32; off > 0; off >>= 1) lin += __shfl_down(lin, off, 64);
    __shared__ float partial[4];
    const int wave = threadIdx.x >> 6;
    const int lane = threadIdx.x & 63;
    if (lane == 0) partial[wave] = lin;
    __syncthreads();
    if (threadIdx.x == 0)
        out[b] = theta_0[0] + partial[0] + partial[1] + partial[2] + partial[3];
}

// ---------------- Kernel 2: masked pairwise quadratic form -----------------
// quad[b] = sum_{l1<l2} Theta[l1,s1,l2,s2]. Inverted decomposition: block
// (c, g) owns rows {g, 254-g} and every NC-th 8-wide l2-chunk of the pair's
// combined chunk list (L in {32,33} -> 4 or 5 chunks/block, balanced).
// Each chunk table (8x20x20 f32, 12.8 KB) staged ONCE via global_load_lds,
// then all 4096 batches gathered (thread t: batches b = i*512+t, i<8).
// MODE 0: block writes a private partial row to `part` (no atomics);
// MODE 1: fallback atomicAdd into out (small ws).
#define QT 512
#define NC 8
#define NMC 32                // 8-wide chunks per row
#define NQUADS 800            // 3200 f32 / 4
#define SEGS 13               // 13 x 1KB wave segments (last 1/4 pad)
#define TBLP (SEGS * 256)     // 3328 f32 (13312 B)

template <int MODE>
__global__ __launch_bounds__(QT, 8) void k_quad(
    const float* __restrict__ Theta,          // (5120, 5120) f32 row-major
    const uint2* __restrict__ seqC,           // [32][4096]
    float* __restrict__ part,                 // [1024][4096] (MODE 0)
    float* __restrict__ out)                  // (MODE 1)
{
    __shared__ float Tl[TBLP];   // 13.3 KB

    const int c   = blockIdx.x;  // 0..7
    const int g   = blockIdx.y;  // 0..127
    const int tid = threadIdx.x;
    const int wave = tid >> 6;
    const int lane = tid & 63;

    const int l1arr[2] = { g, 254 - g };
    const int m0a = (g + 1) >> 3;
    const int m0b = (255 - g) >> 3;
    const int n1 = NMC - m0a;
    const int L  = (g == 127) ? n1 : n1 + (NMC - m0b);

    // per-batch s1*20 for both rows
    int base[2][8];
#pragma unroll
    for (int q = 0; q < 2; ++q) {
        const int l1 = l1arr[q];
        const int mw = l1 >> 3;
        const int wsel = (l1 >> 2) & 1;
        const int sh = (l1 & 3) * 8;
#pragma unroll
        for (int i = 0; i < 8; ++i) {
            const uint2 u = seqC[(size_t)mw * BB + i * QT + tid];
            const unsigned w = wsel ? u.y : u.x;
            base[q][i] = (int)((w >> sh) & 0xFFu) * CCH;
        }
    }

    float acc[8];
#pragma unroll
    for (int i = 0; i < 8; ++i) acc[i] = 0.f;

    for (int t = c; t < L; t += NC) {
        int l1, m, jl, rq;
        if (t < n1) { rq = 0; l1 = l1arr[0]; m = m0a + t;
                      jl = (t == 0) ? ((l1 + 1) & 7) : 0; }
        else        { rq = 1; l1 = l1arr[1]; m = m0b + (t - n1);
                      jl = (t == n1) ? ((l1 + 1) & 7) : 0; }

        __syncthreads();   // prior chunk's gathers complete
        // Stage (l1, m): quad u = seg*64+lane -> elems 4u..4u+3;
        // r = u/5 (= j*20+s1), cc = u%5 -> Theta row l1*20+s1,
        // cols (8m+j)*20 + 4cc..+3. u>799 clamped into LDS pad.
#pragma unroll
        for (int k = 0; k < 2; ++k) {
            const int seg = wave + 8 * k;
            if (seg < SEGS) {
                const int u0 = seg * 64 + lane;
                const int u = (u0 < NQUADS) ? u0 : (NQUADS - 1);
                const int r = u / 5, cc = u - r * 5;
                const int j = r / CCH, s1 = r - j * CCH;
                const float* gp = Theta + (size_t)(l1 * CCH + s1) * LC
                                        + (m * 8 + j) * CCH + cc * 4;
                float* lp = Tl + seg * 256;
                __builtin_amdgcn_global_load_lds(
                    (const __attribute__((address_space(1))) void*)gp,
                    (__attribute__((address_space(3))) void*)lp, 16, 0, 0);
            }
        }
        __syncthreads();   // table ready

        if (jl == 0) {
#pragma unroll
            for (int i = 0; i < 8; ++i) {
                const uint2 u = seqC[(size_t)m * BB + i * QT + tid];
#pragma unroll
                for (int j = 0; j < 8; ++j) {
                    const unsigned w = (j < 4) ? u.x : u.y;
                    const int s2 = (w >> ((j & 3) * 8)) & 0xFF;
                    acc[i] += Tl[j * 400 + base[rq][i] + s2];
                }
            }
        } else {            // ragged first chunk of this row (uniform jl)
#pragma unroll
            for (int i = 0; i < 8; ++i) {
                const uint2 u = seqC[(size_t)m * BB + i * QT + tid];
#pragma unroll
                for (int j = 0; j < 8; ++j) {
                    const unsigned w = (j < 4) ? u.x : u.y;
                    const int s2 = (w >> ((j & 3) * 8)) & 0xFF;
                    const float v = Tl[j * 400 + base[rq][i] + s2];
                    acc[i] += (j >= jl) ? v : 0.f;
                }
            }
        }
    }

    if (MODE == 0) {
        float* row = part + (size_t)(c * 128 + g) * BB;
#pragma unroll
        for (int i = 0; i < 8; ++i) row[i * QT + tid] = acc[i];
    } else {
#pragma unroll
        for (int i = 0; i < 8; ++i) atomicAdd(&out[i * QT + tid], acc[i]);
    }
}

// ---------------- Kernel 3: reduce partial rows into out -------------------
// grid (4, 8): x -> 256 float4 of out, y -> 128 part rows. 8 atomics/word.
__global__ __launch_bounds__(256) void k_reduce(
    const float4* __restrict__ part4,   // [1024][1024]
    float* __restrict__ out)
{
    const int b4 = blockIdx.x * 256 + threadIdx.x;   // < 1024
    const int r0 = blockIdx.y * 128;
    float4 a = make_float4(0.f, 0.f, 0.f, 0.f);
    for (int r = r0; r < r0 + 128; ++r) {
        const float4 p = part4[(size_t)r * 1024 + b4];
        a.x += p.x; a.y += p.y; a.z += p.z; a.w += p.w;
    }
    atomicAdd(&out[b4 * 4 + 0], a.x);
    atomicAdd(&out[b4 * 4 + 1], a.y);
    atomicAdd(&out[b4 * 4 + 2], a.z);
    atomicAdd(&out[b4 * 4 + 3], a.w);
}

extern "C" void kernel_launch(void* const* d_in, const int* in_sizes, int n_in,
                              void* d_out, int out_size, void* d_ws, size_t ws_size,
                              hipStream_t stream) {
    const float* x_lc       = (const float*)d_in[0];
    const float* theta_0    = (const float*)d_in[1];
    const float* theta_lc   = (const float*)d_in[2];
    const float* theta_lclc = (const float*)d_in[3];
    // d_in[4] = mask (bool) — implicit: we only iterate l2 > l1.
    float* out = (float*)d_out;

    unsigned char* seqC = (unsigned char*)d_ws;            // 1 MB
    float* part = (float*)((char*)d_ws + (1 << 20));       // 16.78 MB
    const size_t need = (1 << 20) + (size_t)1024 * BB * 4;

    k_prepare<<<dim3(BB), dim3(256), 0, stream>>>(x_lc, theta_0, theta_lc, seqC, out);
    if (ws_size >= need) {
        k_quad<0><<<dim3(NC, 128), dim3(QT), 0, stream>>>(
            theta_lclc, (const uint2*)seqC, part, out);
        k_reduce<<<dim3(4, 8), dim3(256), 0, stream>>>(
            (const float4*)part, out);
    } else {
        k_quad<1><<<dim3(NC, 128), dim3(QT), 0, stream>>>(
            theta_lclc, (const uint2*)seqC, part, out);
    }
}